// Round 16
// baseline (39.595 us; speedup 1.0000x reference)
//
#include <hip/hip_runtime.h>
#include <math.h>
#include <stdint.h>

#define NTOK 8192
#define HID  4096
#define NEXP 64
#define TOPK 8

typedef float    f32x4 __attribute__((ext_vector_type(4)));
typedef _Float16 f16x8 __attribute__((ext_vector_type(8)));

// ws layout:
//   [0, 1MB)   : wq — W packed as MFMA B-fragments, f16 hi/lo, x2048 scale.
//                16B entry: gs*512 + E*128 + bank*64 + l  (gs = 32-k step 0..127,
//                E = expert-tile 0..3, bank 0=hi 1=lo, l = lane).
//                Element: expert e = E*16+(l&15), k = gs*32+(l>>4)*8+j.
//                Chunk for one gs = 8 KB contiguous -> linear gll.
//   [1MB, 9MB) : lgp — logit partials [4][NTOK][64] f32 (x2048 scale)

__device__ __forceinline__ void cvt_hilo(f32x4 a, f32x4 b, f16x8& hi, f16x8& lo)
{
    float x[8] = {a.x, a.y, a.z, a.w, b.x, b.y, b.z, b.w};
#pragma unroll
    for (int j = 0; j < 8; ++j) {
        const _Float16 h = (_Float16)x[j];
        hi[j] = h;
        lo[j] = (_Float16)(x[j] - (float)h);
    }
}

__device__ __forceinline__ void gll16(const void* g, void* l) {
    __builtin_amdgcn_global_load_lds(
        (const __attribute__((address_space(1))) uint32_t*)g,
        (__attribute__((address_space(3))) uint32_t*)l, 16, 0, 0);
}

#define MFMA16(AH, BH, AC) \
    AC = __builtin_amdgcn_mfma_f32_16x16x32_f16(AH, BH, AC, 0, 0, 0)

// ---------------------------------------------------------------------
// k0: W fp32 -> packed B-fragments (x2048). 128 blocks x 256 thr. (proven)
// ---------------------------------------------------------------------
__global__ __launch_bounds__(256)
void k0_pack(const float* __restrict__ W, f16x8* __restrict__ wq)
{
    const int gidx = blockIdx.x * 256 + threadIdx.x;   // 0..32767
    const int s = gidx >> 8;            // k-step 0..127
    const int E = (gidx >> 6) & 3;      // expert tile
    const int l = gidx & 63;            // lane
    const int e = E * 16 + (l & 15);
    const int k = s * 32 + ((l >> 4) << 3);

    const float* src = W + (size_t)e * HID + k;
    const f32x4 w0 = *(const f32x4*)src;
    const f32x4 w1 = *(const f32x4*)(src + 4);
    f16x8 hi, lo;
    cvt_hilo(w0 * 2048.0f, w1 * 2048.0f, hi, lo);

    wq[s * 512 + E * 128 + l]      = hi;   // bank 0
    wq[s * 512 + E * 128 + 64 + l] = lo;   // bank 1
}

// ---------------------------------------------------------------------
// k1: partial logits (x2048).  COALESCED-A, deep-prefetch stream-chunks.
// grid = 512 blocks (tokgrp = b>>2: 64 tokens; ksb = b&3: 1024-k slice)
// x 512 thr (8 waves = 4 tok-groups x 2 exp-groups).  A: 5 x 8 KB slots,
// staged 3 steps ahead (covers ~900-cyc HBM latency); B: 4 x 8 KB slots,
// staged 2 ahead (L2-hot).  Per step — B ISSUED BEFORE A so the FIFO is
// ..., B(S), A(S+1), B(S+1), A(S+2), B(S+2), A(S+3):  exactly 5 ops newer
// than B(S) -> vmcnt(5) drains tile S while keeping full A depth in flight.
//   STAGE_B(S+2), STAGE_A(S+3) -> vmcnt(5) -> s_barrier -> reads/6 MFMA.
// Overwrite safety: A slot (S+3)%5 / B slot (S+2)%4 last read 2 barriers back.
// A-tile: [t(64)][granule o(8)] 16B granules, source-swizzled o^=(t&7)
// -> ds_read conflict-free; gll source = 8 rows x 128 B per instr.
// ---------------------------------------------------------------------
#define STAGE_A(S) \
    gll16(hap + (size_t)(S) * 128,  &LDSB[((S) % 5) * 8192 + tid * 16])
#define STAGE_B(S) \
    gll16(bap + (size_t)(S) * 8192, &LDSB[40960 + ((S) % 4) * 8192 + tid * 16])

#define KSTEP(S, VN) do {                                                     \
    if ((S) + 2 < 32) STAGE_B((S) + 2);                                       \
    if ((S) + 3 < 32) STAGE_A((S) + 3);                                       \
    asm volatile("s_waitcnt vmcnt(" #VN ")" ::: "memory");                    \
    __builtin_amdgcn_sched_barrier(0);                                        \
    __builtin_amdgcn_s_barrier();                                             \
    __builtin_amdgcn_sched_barrier(0);                                        \
    const char* _A = &LDSB[((S) % 5) * 8192];                                 \
    const char* _B = &LDSB[40960 + ((S) % 4) * 8192];                         \
    const f32x4 a0 = *(const f32x4*)&_A[ga0 * 16];                            \
    const f32x4 a1 = *(const f32x4*)&_A[ga1 * 16];                            \
    const f16x8 bh0 = *(const f16x8*)&_B[(E0 * 128 + l) * 16];                \
    const f16x8 bl0 = *(const f16x8*)&_B[(E0 * 128 + 64 + l) * 16];           \
    const f16x8 bh1 = *(const f16x8*)&_B[(E1 * 128 + l) * 16];                \
    const f16x8 bl1 = *(const f16x8*)&_B[(E1 * 128 + 64 + l) * 16];           \
    f16x8 _ah, _al; cvt_hilo(a0, a1, _ah, _al);                               \
    MFMA16(_ah, bh0, acH0); MFMA16(_ah, bh1, acH1);                           \
    MFMA16(_ah, bl0, acC0); MFMA16(_ah, bl1, acC1);                           \
    MFMA16(_al, bh0, acC0); MFMA16(_al, bh1, acC1);                           \
} while (0)

__global__ __launch_bounds__(512, 2)
void k1_logits(const float* __restrict__ Hm, const char* __restrict__ wqc,
               float* __restrict__ lgp)
{
    __shared__ char LDSB[73728];        // A: 5x8KB @0, B: 4x8KB @40960

    const int tid  = threadIdx.x;
    const int wave = tid >> 6;
    const int l    = tid & 63;
    const int kg   = l >> 4;
    const int tg   = wave >> 1;         // token group 0..3 (16 tokens)
    const int eg   = wave & 1;          // expert group 0..1 (32 experts)
    const int E0   = eg * 2;
    const int E1   = eg * 2 + 1;
    const int tokg = blockIdx.x >> 2;
    const int ksb  = blockIdx.x & 3;
    const int tok0 = tokg * 64;
    const int kb   = ksb * 1024;

    // A-frag read granules (step-invariant): t_loc = tg*16+(l&15), c = kg*2+j
    const int tloc = tg * 16 + (l & 15);
    const int ga0  = tloc * 8 + ((kg * 2)     ^ (l & 7));
    const int ga1  = tloc * 8 + ((kg * 2 + 1) ^ (l & 7));

    // staging identities: thread stages granule (t = tid>>3, o = tid&7),
    // source chunk c = o ^ (t&7) -> 8 rows x 128 B contiguous per gll.
    const int st = tid >> 3;
    const int so = tid & 7;
    const char* hap = (const char*)(Hm + (size_t)(tok0 + st) * HID + kb)
                    + ((so ^ (st & 7)) * 16);
    const char* bap = wqc + (size_t)ksb * 262144 + tid * 16;

    f32x4 acH0 = (f32x4)(0.f), acH1 = (f32x4)(0.f);
    f32x4 acC0 = (f32x4)(0.f), acC1 = (f32x4)(0.f);

    // prologue FIFO: A0,B0,A1,B1,A2  (5 ops newer than B0 at step 0's wait)
    STAGE_A(0); STAGE_B(0); STAGE_A(1); STAGE_B(1); STAGE_A(2);

    KSTEP( 0, 5); KSTEP( 1, 5); KSTEP( 2, 5); KSTEP( 3, 5);
    KSTEP( 4, 5); KSTEP( 5, 5); KSTEP( 6, 5); KSTEP( 7, 5);
    KSTEP( 8, 5); KSTEP( 9, 5); KSTEP(10, 5); KSTEP(11, 5);
    KSTEP(12, 5); KSTEP(13, 5); KSTEP(14, 5); KSTEP(15, 5);
    KSTEP(16, 5); KSTEP(17, 5); KSTEP(18, 5); KSTEP(19, 5);
    KSTEP(20, 5); KSTEP(21, 5); KSTEP(22, 5); KSTEP(23, 5);
    KSTEP(24, 5); KSTEP(25, 5); KSTEP(26, 5); KSTEP(27, 5);
    KSTEP(28, 5); KSTEP(29, 4); KSTEP(30, 2); KSTEP(31, 0);

    // C/D: col = l&15 (expert-in-tile), row = (l>>4)*4 + r (token-in-tile)
    const f32x4 v0 = acH0 + acC0;
    const f32x4 v1 = acH1 + acC1;
    float* o = lgp + ((size_t)ksb * NTOK + tok0 + tg * 16) * 64 + eg * 32;
#pragma unroll
    for (int r = 0; r < 4; ++r) {
        const int row = (kg << 2) + r;
        o[row * 64 +      (l & 15)] = v0[r];
        o[row * 64 + 16 + (l & 15)] = v1[r];
    }
}

// ---------------------------------------------------------------------
// k2: fixed-order 4-slice reduce + softmax + top-8 rank-count.
// 2048 blocks x 256 thr; 1 token per wave (proven form).
// ---------------------------------------------------------------------
__global__ __launch_bounds__(256)
void k2_finish(const float* __restrict__ lgp, float* __restrict__ out)
{
    __shared__ __align__(16) float sc[4][64];
    const int tid  = threadIdx.x;
    const int wave = tid >> 6;
    const int lane = tid & 63;
    float* outw = out;
    float* outi = out + (size_t)NTOK * TOPK;

    const int tok = blockIdx.x * 4 + wave;
    const float* p = lgp + (size_t)tok * 64 + lane;
    const size_t SL = (size_t)NTOK * 64;
    const float lgv = ((p[0] + p[SL]) + (p[2 * SL] + p[3 * SL])) * (1.0f / 2048.0f);

    float mx = lgv;
#pragma unroll
    for (int off = 32; off; off >>= 1) mx = fmaxf(mx, __shfl_xor(mx, off));
    const float pv = expf(lgv - mx);
    float ss = pv;
#pragma unroll
    for (int off = 32; off; off >>= 1) ss += __shfl_xor(ss, off);
    ss = __shfl(ss, 0);                 // identical denominator on all lanes
    const float sval = pv / ss;

    sc[wave][lane] = sval;
    __syncthreads();

    int rank = 0;
#pragma unroll
    for (int j4 = 0; j4 < 16; ++j4) {
        const f32x4 v = *(const f32x4*)&sc[wave][j4 * 4];
#pragma unroll
        for (int u = 0; u < 4; ++u) {
            const int j = j4 * 4 + u;
            rank += (v[u] > sval || (v[u] == sval && j < lane)) ? 1 : 0;
        }
    }
    if (rank < TOPK) {
        outw[(size_t)tok * TOPK + rank] = sval;
        outi[(size_t)tok * TOPK + rank] = (float)lane;
    }
}

extern "C" void kernel_launch(void* const* d_in, const int* in_sizes, int n_in,
                              void* d_out, int out_size, void* d_ws, size_t ws_size,
                              hipStream_t stream) {
    (void)in_sizes; (void)n_in; (void)out_size; (void)ws_size;
    const float* h = (const float*)d_in[0];   // [8192, 4096] fp32
    const float* w = (const float*)d_in[1];   // [64, 4096]  fp32
    float* out = (float*)d_out;

    f16x8* wq  = (f16x8*)d_ws;                        // 1 MB packed B-fragments
    float* lgp = (float*)((char*)d_ws + (1 << 20));   // 8 MB partials [4][NTOK][64]

    k0_pack<<<128, 256, 0, stream>>>(w, wq);
    k1_logits<<<512, 512, 0, stream>>>(h, (const char*)wq, lgp);
    k2_finish<<<NTOK / 4, 256, 0, stream>>>(lgp, out);
}